// Round 1
// baseline (72.363 us; speedup 1.0000x reference)
//
#include <hip/hip_runtime.h>
#include <cstddef>

#define NSLOT 128

__device__ __forceinline__ float lrelu(float v) { return v >= 0.0f ? v : 0.01f * v; }

// GCN2Conv constants
#define ALPHA 0.5f
#define B1 0.6931471805599453f   /* log(2)   */
#define B2 0.4054651081081644f   /* log(1.5) */

// Compute post-layer2 (pre-BN) features h2[6 nodes][6 feats] for one graph.
// lw layout: W1[36], b1[6], W2[36], b2[6]
__device__ __forceinline__ void compute_h2(const float* __restrict__ xg,
                                           const float* __restrict__ eg,
                                           const float* __restrict__ lw,
                                           float h2[36]) {
  float xv[36], w[36], t[36];
#pragma unroll
  for (int k = 0; k < 9; ++k) {
    float4 a = reinterpret_cast<const float4*>(xg)[k];
    xv[4*k+0] = a.x; xv[4*k+1] = a.y; xv[4*k+2] = a.z; xv[4*k+3] = a.w;
  }
#pragma unroll
  for (int k = 0; k < 9; ++k) {
    float4 b = reinterpret_cast<const float4*>(eg)[k];
    w[4*k+0] = b.x; w[4*k+1] = b.y; w[4*k+2] = b.z; w[4*k+3] = b.w;
  }
  const float* W1  = lw;
  const float* bb1 = lw + 36;
  const float* W2  = lw + 42;
  const float* bb2 = lw + 78;

  // ---- layer 1: u1 = 0.5*(1/6)*Sum_i ew[i,j]*x[i] + 0.5*x[j] ----
#pragma unroll
  for (int j = 0; j < 6; ++j)
#pragma unroll
    for (int f = 0; f < 6; ++f) {
      float a = 0.0f;
#pragma unroll
      for (int i = 0; i < 6; ++i) a = fmaf(w[i*6+j], xv[i*6+f], a);
      t[j*6+f] = ALPHA * (a * (1.0f/6.0f)) + ALPHA * xv[j*6+f];
    }
  // h1 = lrelu((1-B1)*u1 + B1*(u1@W1) + b1)  -> stored back into xv
#pragma unroll
  for (int j = 0; j < 6; ++j)
#pragma unroll
    for (int f = 0; f < 6; ++f) {
      float a = 0.0f;
#pragma unroll
      for (int k = 0; k < 6; ++k) a = fmaf(t[j*6+k], W1[k*6+f], a);
      xv[j*6+f] = lrelu((1.0f - B1) * t[j*6+f] + B1 * a + bb1[f]);
    }
  // ---- layer 2 (feat0 = h1) ----
#pragma unroll
  for (int j = 0; j < 6; ++j)
#pragma unroll
    for (int f = 0; f < 6; ++f) {
      float a = 0.0f;
#pragma unroll
      for (int i = 0; i < 6; ++i) a = fmaf(w[i*6+j], xv[i*6+f], a);
      t[j*6+f] = ALPHA * (a * (1.0f/6.0f)) + ALPHA * xv[j*6+f];
    }
#pragma unroll
  for (int j = 0; j < 6; ++j)
#pragma unroll
    for (int f = 0; f < 6; ++f) {
      float a = 0.0f;
#pragma unroll
      for (int k = 0; k < 6; ++k) a = fmaf(t[j*6+k], W2[k*6+f], a);
      h2[j*6+f] = (1.0f - B2) * t[j*6+f] + B2 * a + bb2[f];
    }
}

__global__ __launch_bounds__(256) void gcn2_pass1(
    const float* __restrict__ x, const float* __restrict__ ew,
    const float* __restrict__ W1, const float* __restrict__ b1,
    const float* __restrict__ W2, const float* __restrict__ b2,
    float* __restrict__ wsred, int G) {
  __shared__ float lw[84];
  const int tid = threadIdx.x;
  if (tid < 84) {
    float v;
    if (tid < 36)      v = W1[tid];
    else if (tid < 42) v = b1[tid - 36];
    else if (tid < 78) v = W2[tid - 42];
    else               v = b2[tid - 78];
    lw[tid] = v;
  }
  __syncthreads();

  const int g = blockIdx.x * 256 + tid;
  float s[6]  = {0.f,0.f,0.f,0.f,0.f,0.f};
  float ss[6] = {0.f,0.f,0.f,0.f,0.f,0.f};
  if (g < G) {
    float h2[36];
    compute_h2(x + (size_t)g * 36, ew + (size_t)g * 36, lw, h2);
#pragma unroll
    for (int f = 0; f < 6; ++f) {
#pragma unroll
      for (int j = 0; j < 6; ++j) {
        float v = h2[j*6+f];
        s[f]  += v;
        ss[f]  = fmaf(v, v, ss[f]);
      }
    }
  }
  // wave64 reduction of 12 partials
#pragma unroll
  for (int f = 0; f < 6; ++f) {
#pragma unroll
    for (int o = 32; o >= 1; o >>= 1) {
      s[f]  += __shfl_down(s[f],  (unsigned)o, 64);
      ss[f] += __shfl_down(ss[f], (unsigned)o, 64);
    }
  }
  if ((tid & 63) == 0) {
    const int wid = blockIdx.x * 4 + (tid >> 6);
    float* p = wsred + (size_t)(wid & (NSLOT - 1)) * 12;
#pragma unroll
    for (int f = 0; f < 6; ++f) {
      atomicAdd(p + f,     s[f]);
      atomicAdd(p + 6 + f, ss[f]);
    }
  }
}

// Reduce NSLOT partial slots -> per-feature scale/shift for fused BN
__global__ void gcn2_finalize(const float* __restrict__ wsred,
                              const float* __restrict__ gamma,
                              const float* __restrict__ beta_bn,
                              float* __restrict__ stats, float invN) {
  __shared__ float tot[12];
  const int t = threadIdx.x;
  if (t < 12) {
    float a = 0.0f;
    for (int sIdx = 0; sIdx < NSLOT; ++sIdx) a += wsred[sIdx * 12 + t];
    tot[t] = a;
  }
  __syncthreads();
  if (t < 6) {
    float mean = tot[t] * invN;
    float var  = tot[6 + t] * invN - mean * mean;
    float istd = rsqrtf(var + 1e-5f);
    float sc   = istd * gamma[t];
    stats[t]     = sc;
    stats[6 + t] = beta_bn[t] - mean * sc;
  }
}

__global__ __launch_bounds__(256) void gcn2_pass2(
    const float* __restrict__ x, const float* __restrict__ ew,
    const float* __restrict__ W1, const float* __restrict__ b1,
    const float* __restrict__ W2, const float* __restrict__ b2,
    const float* __restrict__ fcW1, const float* __restrict__ fcb1,
    const float* __restrict__ fcW2, const float* __restrict__ fcb2,
    const float* __restrict__ stats, float* __restrict__ out, int G) {
  __shared__ float lw[188];
  const int tid = threadIdx.x;
  if (tid < 188) {
    float v;
    if (tid < 36)       v = W1[tid];
    else if (tid < 42)  v = b1[tid - 36];
    else if (tid < 78)  v = W2[tid - 42];
    else if (tid < 84)  v = b2[tid - 78];
    else if (tid < 144) v = fcW1[tid - 84];
    else if (tid < 154) v = fcb1[tid - 144];
    else if (tid < 174) v = fcW2[tid - 154];
    else if (tid < 176) v = fcb2[tid - 174];
    else                v = stats[tid - 176];
    lw[tid] = v;
  }
  __syncthreads();

  const int g = blockIdx.x * 256 + tid;
  if (g >= G) return;

  float h2[36];
  compute_h2(x + (size_t)g * 36, ew + (size_t)g * 36, lw, h2);

  const float* scale = lw + 176;
  const float* shift = lw + 182;
  float pooled[6] = {0.f,0.f,0.f,0.f,0.f,0.f};
#pragma unroll
  for (int j = 0; j < 6; ++j)
#pragma unroll
    for (int f = 0; f < 6; ++f)
      pooled[f] += lrelu(fmaf(h2[j*6+f], scale[f], shift[f]));

  const float* fw1 = lw + 84;
  const float* fb1 = lw + 144;
  const float* fw2 = lw + 154;
  const float* fb2 = lw + 174;
  float p1[10];
#pragma unroll
  for (int m = 0; m < 10; ++m) {
    float a = fb1[m];
#pragma unroll
    for (int f = 0; f < 6; ++f) a = fmaf(pooled[f], fw1[f*10+m], a);
    p1[m] = lrelu(a);
  }
  float o0 = fb2[0], o1 = fb2[1];
#pragma unroll
  for (int m = 0; m < 10; ++m) {
    o0 = fmaf(p1[m], fw2[m*2+0], o0);
    o1 = fmaf(p1[m], fw2[m*2+1], o1);
  }
  reinterpret_cast<float2*>(out)[g] = make_float2(o0, o1);
}

extern "C" void kernel_launch(void* const* d_in, const int* in_sizes, int n_in,
                              void* d_out, int out_size, void* d_ws, size_t ws_size,
                              hipStream_t stream) {
  const float* x      = (const float*)d_in[0];
  const float* ew     = (const float*)d_in[1];
  const float* W1     = (const float*)d_in[2];
  const float* b1     = (const float*)d_in[3];
  const float* W2     = (const float*)d_in[4];
  const float* b2     = (const float*)d_in[5];
  const float* gamma  = (const float*)d_in[6];
  const float* beta   = (const float*)d_in[7];
  const float* fcW1   = (const float*)d_in[8];
  const float* fcb1   = (const float*)d_in[9];
  const float* fcW2   = (const float*)d_in[10];
  const float* fcb2   = (const float*)d_in[11];

  const int G = in_sizes[0] / 36;        // x is [6G, 6]

  float* wsred = (float*)d_ws;           // NSLOT*12 accumulators
  float* stats = wsred + NSLOT * 12;     // scale[6], shift[6]

  hipMemsetAsync(d_ws, 0, NSLOT * 12 * sizeof(float), stream);

  const int block = 256;
  const int grid  = (G + block - 1) / block;
  gcn2_pass1<<<grid, block, 0, stream>>>(x, ew, W1, b1, W2, b2, wsred, G);
  gcn2_finalize<<<1, 64, 0, stream>>>(wsred, gamma, beta,
                                      stats, 1.0f / (6.0f * (float)G));
  gcn2_pass2<<<grid, block, 0, stream>>>(x, ew, W1, b1, W2, b2,
                                         fcW1, fcb1, fcW2, fcb2,
                                         stats, (float*)d_out, G);
}